// Round 3
// baseline (433.643 us; speedup 1.0000x reference)
//
#include <hip/hip_runtime.h>

#define N_NODES  100000
#define N_EDGES  1200000
#define N_GRAPHS 1024

#define EDGE_BLOCKS ((N_EDGES + 255) / 256)   // 4688
#define ENC_BLOCKS  ((N_NODES + 15) / 16)     // 6250 (16 nodes/block)

// ---- fused: edge blocks build {deg histogram + linked list}; enc blocks do
//      encoder + BN + h@W_gcn -> hw. Independent work overlapped in one launch.
__global__ __launch_bounds__(256) void k_front(
    const float* __restrict__ x,
    const float* __restrict__ Wenc, const float* __restrict__ benc,
    const float* __restrict__ gamma, const float* __restrict__ beta,
    const float* __restrict__ mean,  const float* __restrict__ var,
    const float* __restrict__ Wgcn,
    const int* __restrict__ ei,
    float* __restrict__ hw,
    int* __restrict__ deg, int* __restrict__ head, int* __restrict__ nxt) {
  if (blockIdx.x < EDGE_BLOCKS) {
    int e = blockIdx.x * 256 + threadIdx.x;
    if (e < N_EDGES) {
      int dst = ei[N_EDGES + e];
      atomicAdd(&deg[dst], 1);
      int prev = atomicExch(&head[dst], e);   // push edge onto dst's list
      nxt[e] = prev;                          // coalesced write
    }
    return;
  }
  // ---------------- encoder part ----------------
  __shared__ float wLDS[64 * 64];
  __shared__ float hLDS[256];
  int tid = threadIdx.x;
  for (int i = tid; i < 64 * 64; i += 256) wLDS[i] = Wgcn[i];
  int lane = tid & 63;
  int grp  = tid >> 6;
  float be = benc[lane];
  float sc = gamma[lane] * rsqrtf(var[lane] + 1e-5f);
  float mu = mean[lane], bt = beta[lane];
  float w0 = Wenc[lane], w1 = Wenc[64 + lane], w2 = Wenc[128 + lane], w3 = Wenc[192 + lane];
  int nblk = blockIdx.x - EDGE_BLOCKS;
  for (int it = 0; it < 4; ++it) {
    int node = nblk * 16 + it * 4 + grp;
    float hbn = 0.f;
    if (node < N_NODES) {
      float4 xv = ((const float4*)x)[node];
      float h = be + xv.x * w0 + xv.y * w1 + xv.z * w2 + xv.w * w3;
      h = fmaxf(h, 0.f);                 // ReLU (dropout = identity)
      hbn = (h - mu) * sc + bt;          // BatchNorm (running stats)
    }
    __syncthreads();
    hLDS[tid] = hbn;
    __syncthreads();
    if (node < N_NODES) {
      float acc = 0.f;
      const float* hp = &hLDS[grp * 64];
      #pragma unroll
      for (int k = 0; k < 64; ++k) acc += hp[k] * wLDS[k * 64 + lane];
      hw[(size_t)node * 64 + lane] = acc;
    }
  }
}

// ---- dis = rsqrt(deg+1); gcnt histogram ----
__global__ void k_dis(const int* __restrict__ deg, const int* __restrict__ batch,
                      float* __restrict__ dis, float* __restrict__ gcnt) {
  int i = blockIdx.x * 256 + threadIdx.x;
  if (i < N_NODES) {
    dis[i] = rsqrtf((float)(deg[i] + 1));   // +1 self-loop
    atomicAdd(&gcnt[batch[i]], 1.0f);
  }
}

// ---- chain-walk gather, 4 nodes (chains) per wave for MLP; fused
//      self-loop + bias + ReLU + mean-pool atomic ----
__global__ __launch_bounds__(256) void k_gather(
    const int* __restrict__ head, const int* __restrict__ nxt,
    const int* __restrict__ ei, const float* __restrict__ dis,
    const float* __restrict__ hw, const int* __restrict__ batch,
    const float* __restrict__ bgcn, float* __restrict__ gsum) {
  int lane = threadIdx.x & 63;
  int w = blockIdx.x * 4 + (threadIdx.x >> 6);
  int nb = w * 4;
  if (nb >= N_NODES) return;
  int e0 = head[nb];
  int e1 = (nb + 1 < N_NODES) ? head[nb + 1] : -1;
  int e2 = (nb + 2 < N_NODES) ? head[nb + 2] : -1;
  int e3 = (nb + 3 < N_NODES) ? head[nb + 3] : -1;
  float a0 = 0.f, a1 = 0.f, a2 = 0.f, a3 = 0.f;
  // norm factored: dis[src]*dis[dst] -> accumulate dis[src]*hw[src], scale by dn at end
  while ((e0 >= 0) | (e1 >= 0) | (e2 >= 0) | (e3 >= 0)) {
    if (e0 >= 0) { int s = ei[e0]; float d = dis[s]; a0 += hw[(size_t)s * 64 + lane] * d; e0 = nxt[e0]; }
    if (e1 >= 0) { int s = ei[e1]; float d = dis[s]; a1 += hw[(size_t)s * 64 + lane] * d; e1 = nxt[e1]; }
    if (e2 >= 0) { int s = ei[e2]; float d = dis[s]; a2 += hw[(size_t)s * 64 + lane] * d; e2 = nxt[e2]; }
    if (e3 >= 0) { int s = ei[e3]; float d = dis[s]; a3 += hw[(size_t)s * 64 + lane] * d; e3 = nxt[e3]; }
  }
  float bias = bgcn[lane];
  {
    int n = nb;
    float dn = dis[n];
    float v = fmaxf(dn * (a0 + dn * hw[(size_t)n * 64 + lane]) + bias, 0.f);
    atomicAdd(&gsum[batch[n] * 64 + lane], v);
  }
  if (nb + 1 < N_NODES) {
    int n = nb + 1;
    float dn = dis[n];
    float v = fmaxf(dn * (a1 + dn * hw[(size_t)n * 64 + lane]) + bias, 0.f);
    atomicAdd(&gsum[batch[n] * 64 + lane], v);
  }
  if (nb + 2 < N_NODES) {
    int n = nb + 2;
    float dn = dis[n];
    float v = fmaxf(dn * (a2 + dn * hw[(size_t)n * 64 + lane]) + bias, 0.f);
    atomicAdd(&gsum[batch[n] * 64 + lane], v);
  }
  if (nb + 3 < N_NODES) {
    int n = nb + 3;
    float dn = dis[n];
    float v = fmaxf(dn * (a3 + dn * hw[(size_t)n * 64 + lane]) + bias, 0.f);
    atomicAdd(&gsum[batch[n] * 64 + lane], v);
  }
}

// ---------------- classifier: gm -> Linear+ReLU -> Linear ----------------
__global__ void k_cls(const float* __restrict__ gsum, const float* __restrict__ gcnt,
                      const float* __restrict__ W1, const float* __restrict__ b1,
                      const float* __restrict__ W2, const float* __restrict__ b2,
                      float* __restrict__ out) {
  __shared__ float gm[64];
  int j = threadIdx.x;
  int g = blockIdx.x;
  float denom = fmaxf(gcnt[g], 1.0f);
  gm[j] = gsum[g * 64 + j] / denom;
  __syncthreads();
  float hid = b1[j];
  #pragma unroll
  for (int k = 0; k < 64; ++k) hid += gm[k] * W1[k * 64 + j];
  hid = fmaxf(hid, 0.f);
  float o0 = hid * W2[j * 2 + 0];
  float o1 = hid * W2[j * 2 + 1];
  #pragma unroll
  for (int off = 32; off > 0; off >>= 1) {
    o0 += __shfl_down(o0, off);
    o1 += __shfl_down(o1, off);
  }
  if (j == 0) {
    out[g * 2 + 0] = o0 + b2[0];
    out[g * 2 + 1] = o1 + b2[1];
  }
}

extern "C" void kernel_launch(void* const* d_in, const int* in_sizes, int n_in,
                              void* d_out, int out_size, void* d_ws, size_t ws_size,
                              hipStream_t stream) {
  const float* x     = (const float*)d_in[0];
  const int*   ei    = (const int*)d_in[1];
  const int*   batch = (const int*)d_in[2];
  const float* Wenc  = (const float*)d_in[3];
  const float* benc  = (const float*)d_in[4];
  const float* gamma = (const float*)d_in[5];
  const float* beta  = (const float*)d_in[6];
  const float* mean  = (const float*)d_in[7];
  const float* var   = (const float*)d_in[8];
  const float* Wgcn  = (const float*)d_in[9];
  const float* bgcn  = (const float*)d_in[10];
  const float* W1    = (const float*)d_in[11];
  const float* b1    = (const float*)d_in[12];
  const float* W2    = (const float*)d_in[13];
  const float* b2    = (const float*)d_in[14];
  float* out = (float*)d_out;

  char* ws = (char*)d_ws;
  int*   deg  = (int*)ws;                ws += (size_t)N_NODES * 4;
  int*   head = (int*)ws;                ws += (size_t)N_NODES * 4;
  int*   nxt  = (int*)ws;                ws += (size_t)N_EDGES * 4;
  float* dis  = (float*)ws;              ws += (size_t)N_NODES * 4;
  float* hw   = (float*)ws;              ws += (size_t)N_NODES * 64 * 4;
  float* gsum = (float*)ws;              ws += (size_t)N_GRAPHS * 64 * 4;
  float* gcnt = (float*)ws;              ws += (size_t)N_GRAPHS * 4;

  hipMemsetAsync(deg, 0, (size_t)N_NODES * 4, stream);
  hipMemsetAsync(head, 0xFF, (size_t)N_NODES * 4, stream);   // -1 sentinels
  hipMemsetAsync(gsum, 0, (size_t)(N_GRAPHS * 64 + N_GRAPHS) * 4, stream);

  k_front<<<EDGE_BLOCKS + ENC_BLOCKS, 256, 0, stream>>>(
      x, Wenc, benc, gamma, beta, mean, var, Wgcn, ei, hw, deg, head, nxt);
  k_dis<<<(N_NODES + 255) / 256, 256, 0, stream>>>(deg, batch, dis, gcnt);
  int waves = (N_NODES + 3) / 4;
  k_gather<<<(waves + 3) / 4, 256, 0, stream>>>(head, nxt, ei, dis, hw, batch, bgcn, gsum);
  k_cls<<<N_GRAPHS, 64, 0, stream>>>(gsum, gcnt, W1, b1, W2, b2, out);
}

// Round 4
// 282.615 us; speedup vs baseline: 1.5344x; 1.5344x over previous
//
#include <hip/hip_runtime.h>

#define N_NODES  100000
#define N_EDGES  1200000
#define N_GRAPHS 1024

#define BUCK_SHIFT 10
#define BUCK_NODES 1024
#define NBUCK 98                     // ceil(100000/1024)
#define BIN_BLOCKS 256
#define BIN_CHUNK ((N_EDGES + BIN_BLOCKS - 1) / BIN_BLOCKS)   // 4688
#define STAGE_CAP 64
#define DRAIN_THRESH 48

// ---- bucket histogram: bcnt[b] = #edges with dst in bucket b ----
__global__ __launch_bounds__(256) void k_cnt(const int* __restrict__ ei,
                                             int* __restrict__ bcnt) {
  __shared__ int h[NBUCK];
  for (int i = threadIdx.x; i < NBUCK; i += 256) h[i] = 0;
  __syncthreads();
  int start = blockIdx.x * BIN_CHUNK;
  int end = min(start + BIN_CHUNK, N_EDGES);
  for (int e = start + threadIdx.x; e < end; e += 256)
    atomicAdd(&h[ei[N_EDGES + e] >> BUCK_SHIFT], 1);
  __syncthreads();
  for (int i = threadIdx.x; i < NBUCK; i += 256)
    if (h[i]) atomicAdd(&bcnt[i], h[i]);
}

// ---- exclusive scan of 98 bucket counts ----
__global__ void k_scan(const int* __restrict__ bcnt, int* __restrict__ gbase,
                       int* __restrict__ gcur) {
  __shared__ int s[128];
  int t = threadIdx.x;
  int v = (t < NBUCK) ? bcnt[t] : 0;
  s[t] = v;
  __syncthreads();
  for (int off = 1; off < 128; off <<= 1) {
    int x = (t >= off) ? s[t - off] : 0;
    __syncthreads();
    s[t] += x;
    __syncthreads();
  }
  if (t < NBUCK) {
    int excl = s[t] - v;
    gbase[t] = excl;
    gcur[t] = excl;
  }
  if (t == 0) gbase[NBUCK] = N_EDGES;
}

// ---- LDS-staged binning: binned grouped by bucket, packed src|dstlow<<17 ----
__global__ __launch_bounds__(256) void k_bin(const int* __restrict__ ei,
                                             int* __restrict__ gcur,
                                             int* __restrict__ binned) {
  __shared__ int lcnt[NBUCK];
  __shared__ int lbase[NBUCK];
  __shared__ int lout[NBUCK];
  __shared__ int lbuf[NBUCK][STAGE_CAP];
  for (int i = threadIdx.x; i < NBUCK; i += 256) lcnt[i] = 0;
  __syncthreads();
  int start = blockIdx.x * BIN_CHUNK;
  int end = min(start + BIN_CHUNK, N_EDGES);
  int iters = (end - start + 255) / 256;     // uniform within block
  int lane = threadIdx.x & 63, w = threadIdx.x >> 6;
  for (int it = 0; it < iters; ++it) {
    int e = start + it * 256 + threadIdx.x;
    if (e < end) {
      int src = ei[e];
      int dst = ei[N_EDGES + e];
      int b = dst >> BUCK_SHIFT;
      int val = src | ((dst & (BUCK_NODES - 1)) << 17);
      int pos = atomicAdd(&lcnt[b], 1);
      if (pos < STAGE_CAP) lbuf[b][pos] = val;
      else binned[atomicAdd(&gcur[b], 1)] = val;     // rare overflow fallback
    }
    __syncthreads();
    bool last = (it == iters - 1);
    if (threadIdx.x < NBUCK) {
      int c = lcnt[threadIdx.x];
      int stored = min(c, STAGE_CAP);
      int d = (last || c >= DRAIN_THRESH) ? stored : 0;
      lout[threadIdx.x] = d;
      if (d) {
        lbase[threadIdx.x] = atomicAdd(&gcur[threadIdx.x], d);
        lcnt[threadIdx.x] = 0;
      }
    }
    __syncthreads();
    for (int b = w; b < NBUCK; b += 4) {       // wave-parallel coalesced drain
      int d = lout[b];
      if (d) {
        int gb = lbase[b];
        for (int i = lane; i < d; i += 64) binned[gb + i] = lbuf[b][i];
      }
    }
    __syncthreads();
  }
}

// ---- per-bucket: LDS hist+scan -> row_start/dis (coalesced), sort csr ----
__global__ __launch_bounds__(512) void k_csr(const int* __restrict__ gbase,
                                             const int* __restrict__ binned,
                                             int* __restrict__ csr,
                                             int* __restrict__ row_start,
                                             float* __restrict__ dis) {
  __shared__ int hist[BUCK_NODES];
  __shared__ int rs[BUCK_NODES];
  __shared__ int wsum[8];
  int t = threadIdx.x;
  int blk = blockIdx.x;
  int base = gbase[blk];
  int nE = gbase[blk + 1] - base;
  int node0 = blk << BUCK_SHIFT;
  int nNodes = min(BUCK_NODES, N_NODES - node0);
  hist[t] = 0; hist[t + 512] = 0;
  __syncthreads();
  for (int i = t; i < nE; i += 512)
    atomicAdd(&hist[(unsigned)binned[base + i] >> 17], 1);
  __syncthreads();
  // exclusive scan hist[0..1023] -> rs (each thread owns 2 elements)
  int x0 = hist[2 * t], x1 = hist[2 * t + 1];
  int a = x0 + x1;
  int lane = t & 63, w = t >> 6;
  int incl = a;
  for (int off = 1; off < 64; off <<= 1) {
    int y = __shfl_up(incl, off);
    if (lane >= off) incl += y;
  }
  if (lane == 63) wsum[w] = incl;
  __syncthreads();
  if (w == 0) {
    int v = (lane < 8) ? wsum[lane] : 0;
    for (int off = 1; off < 8; off <<= 1) {
      int y = __shfl_up(v, off);
      if (lane >= off) v += y;
    }
    if (lane < 8) wsum[lane] = v;
  }
  __syncthreads();
  int woff = (w > 0) ? wsum[w - 1] : 0;
  int exclPair = woff + incl - a;
  rs[2 * t] = exclPair;
  rs[2 * t + 1] = exclPair + x0;
  __syncthreads();
  for (int n = t; n < BUCK_NODES; n += 512) {
    int cnt = ((n < BUCK_NODES - 1) ? rs[n + 1] : nE) - rs[n];
    hist[n] = rs[n];                           // reuse hist as scatter cursor
    if (n < nNodes) {
      row_start[node0 + n] = base + rs[n];
      dis[node0 + n] = rsqrtf((float)(cnt + 1));   // +1 self-loop
    }
  }
  if (t == 0 && blk == NBUCK - 1) row_start[N_NODES] = N_EDGES;
  __syncthreads();
  for (int i = t; i < nE; i += 512) {
    int v = binned[base + i];
    int d = (unsigned)v >> 17;
    int p = atomicAdd(&hist[d], 1);
    csr[base + p] = v & 0x1FFFF;               // scatter confined to ~49KB region
  }
}

// ---- encoder + BN + h@W_gcn, pre-scaled by dis[node] -> hws ----
__global__ __launch_bounds__(256) void k_enc(
    const float* __restrict__ x,
    const float* __restrict__ Wenc, const float* __restrict__ benc,
    const float* __restrict__ gamma, const float* __restrict__ beta,
    const float* __restrict__ mean,  const float* __restrict__ var,
    const float* __restrict__ Wgcn,  const float* __restrict__ dis,
    float* __restrict__ hws) {
  __shared__ float wLDS[64 * 64];
  __shared__ float hLDS[256];
  int tid = threadIdx.x;
  for (int i = tid; i < 64 * 64; i += 256) wLDS[i] = Wgcn[i];
  int lane = tid & 63;
  int grp  = tid >> 6;
  float be = benc[lane];
  float sc = gamma[lane] * rsqrtf(var[lane] + 1e-5f);
  float mu = mean[lane], bt = beta[lane];
  float w0 = Wenc[lane], w1 = Wenc[64 + lane], w2 = Wenc[128 + lane], w3 = Wenc[192 + lane];
  for (int it = 0; it < 4; ++it) {
    int node = blockIdx.x * 16 + it * 4 + grp;
    float hbn = 0.f;
    if (node < N_NODES) {
      float4 xv = ((const float4*)x)[node];
      float h = be + xv.x * w0 + xv.y * w1 + xv.z * w2 + xv.w * w3;
      h = fmaxf(h, 0.f);                 // ReLU (dropout = identity)
      hbn = (h - mu) * sc + bt;          // BatchNorm (running stats)
    }
    __syncthreads();
    hLDS[tid] = hbn;
    __syncthreads();
    if (node < N_NODES) {
      float acc = 0.f;
      const float* hp = &hLDS[grp * 64];
      #pragma unroll
      for (int k = 0; k < 64; ++k) acc += hp[k] * wLDS[k * 64 + lane];
      hws[(size_t)node * 64 + lane] = acc * dis[node];
    }
  }
}

// ---- CSR gather: 4 consecutive nodes/wave, 4-acc ILP, merged pool atomics ----
__global__ __launch_bounds__(256) void k_gather(
    const int* __restrict__ row_start, const int* __restrict__ csr,
    const float* __restrict__ dis, const float* __restrict__ hws,
    const int* __restrict__ batch, const float* __restrict__ bgcn,
    float* __restrict__ gsum) {
  int lane = threadIdx.x & 63;
  int wv = blockIdx.x * 4 + (threadIdx.x >> 6);
  int nb = wv * 4;                       // 100000 = 4*25000, no tail
  if (nb >= N_NODES) return;
  float bias = bgcn[lane];
  float vout[4];
  int gid[4];
  #pragma unroll
  for (int k = 0; k < 4; ++k) {
    int n = nb + k;
    int st = row_start[n], en = row_start[n + 1];
    float dn = dis[n];
    float a0 = 0.f, a1 = 0.f, a2 = 0.f, a3 = 0.f;
    for (int c = st; c < en; c += 64) {
      int idx = c + lane;
      int sj = (idx < en) ? csr[idx] : 0;
      int m = min(64, en - c);
      int j = 0;
      for (; j + 4 <= m; j += 4) {
        int s0 = __shfl(sj, j), s1 = __shfl(sj, j + 1);
        int s2 = __shfl(sj, j + 2), s3 = __shfl(sj, j + 3);
        a0 += hws[(size_t)s0 * 64 + lane];
        a1 += hws[(size_t)s1 * 64 + lane];
        a2 += hws[(size_t)s2 * 64 + lane];
        a3 += hws[(size_t)s3 * 64 + lane];
      }
      for (; j < m; ++j) {
        int s = __shfl(sj, j);
        a0 += hws[(size_t)s * 64 + lane];
      }
    }
    float self = hws[(size_t)n * 64 + lane];
    vout[k] = fmaxf(dn * (((a0 + a1) + (a2 + a3)) + self) + bias, 0.f);
    gid[k] = batch[n];
  }
  float vs = vout[0];
  int cg = gid[0];
  #pragma unroll
  for (int k = 1; k < 4; ++k) {
    if (gid[k] == cg) vs += vout[k];
    else {
      atomicAdd(&gsum[cg * 64 + lane], vs);
      vs = vout[k]; cg = gid[k];
    }
  }
  atomicAdd(&gsum[cg * 64 + lane], vs);
}

// ---- classifier; graph count via binary search on sorted batch ----
__global__ void k_cls(const float* __restrict__ gsum, const int* __restrict__ batch,
                      const float* __restrict__ W1, const float* __restrict__ b1,
                      const float* __restrict__ W2, const float* __restrict__ b2,
                      float* __restrict__ out) {
  __shared__ float gm[64];
  __shared__ int cntS;
  int j = threadIdx.x;
  int g = blockIdx.x;
  if (j == 0) {
    int lo = 0, hi = N_NODES;
    while (lo < hi) { int mid = (lo + hi) >> 1; if (batch[mid] < g) lo = mid + 1; else hi = mid; }
    int lo2 = lo, hi2 = N_NODES;
    while (lo2 < hi2) { int mid = (lo2 + hi2) >> 1; if (batch[mid] < g + 1) lo2 = mid + 1; else hi2 = mid; }
    cntS = lo2 - lo;
  }
  __syncthreads();
  float denom = fmaxf((float)cntS, 1.0f);
  gm[j] = gsum[g * 64 + j] / denom;
  __syncthreads();
  float hid = b1[j];
  #pragma unroll
  for (int k = 0; k < 64; ++k) hid += gm[k] * W1[k * 64 + j];
  hid = fmaxf(hid, 0.f);
  float o0 = hid * W2[j * 2 + 0];
  float o1 = hid * W2[j * 2 + 1];
  #pragma unroll
  for (int off = 32; off > 0; off >>= 1) {
    o0 += __shfl_down(o0, off);
    o1 += __shfl_down(o1, off);
  }
  if (j == 0) {
    out[g * 2 + 0] = o0 + b2[0];
    out[g * 2 + 1] = o1 + b2[1];
  }
}

extern "C" void kernel_launch(void* const* d_in, const int* in_sizes, int n_in,
                              void* d_out, int out_size, void* d_ws, size_t ws_size,
                              hipStream_t stream) {
  const float* x     = (const float*)d_in[0];
  const int*   ei    = (const int*)d_in[1];
  const int*   batch = (const int*)d_in[2];
  const float* Wenc  = (const float*)d_in[3];
  const float* benc  = (const float*)d_in[4];
  const float* gamma = (const float*)d_in[5];
  const float* beta  = (const float*)d_in[6];
  const float* mean  = (const float*)d_in[7];
  const float* var   = (const float*)d_in[8];
  const float* Wgcn  = (const float*)d_in[9];
  const float* bgcn  = (const float*)d_in[10];
  const float* W1    = (const float*)d_in[11];
  const float* b1    = (const float*)d_in[12];
  const float* W2    = (const float*)d_in[13];
  const float* b2    = (const float*)d_in[14];
  float* out = (float*)d_out;

  char* ws = (char*)d_ws;
  float* gsum      = (float*)ws;  ws += (size_t)N_GRAPHS * 64 * 4;
  int*   bcnt      = (int*)ws;    ws += 128 * 4;
  int*   gbase     = (int*)ws;    ws += 128 * 4;
  int*   gcur      = (int*)ws;    ws += 128 * 4;
  int*   binned    = (int*)ws;    ws += (size_t)N_EDGES * 4;
  int*   csr       = (int*)ws;    ws += (size_t)N_EDGES * 4;
  int*   row_start = (int*)ws;    ws += (size_t)(N_NODES + 32) * 4;
  float* dis       = (float*)ws;  ws += (size_t)N_NODES * 4;
  float* hws       = (float*)ws;  ws += (size_t)N_NODES * 64 * 4;

  // gsum and bcnt are adjacent: single memset
  hipMemsetAsync(gsum, 0, ((size_t)N_GRAPHS * 64 + 128) * 4, stream);

  k_cnt<<<BIN_BLOCKS, 256, 0, stream>>>(ei, bcnt);
  k_scan<<<1, 128, 0, stream>>>(bcnt, gbase, gcur);
  k_bin<<<BIN_BLOCKS, 256, 0, stream>>>(ei, gcur, binned);
  k_csr<<<NBUCK, 512, 0, stream>>>(gbase, binned, csr, row_start, dis);
  k_enc<<<(N_NODES + 15) / 16, 256, 0, stream>>>(x, Wenc, benc, gamma, beta, mean, var,
                                                 Wgcn, dis, hws);
  k_gather<<<(N_NODES / 16), 256, 0, stream>>>(row_start, csr, dis, hws, batch, bgcn, gsum);
  k_cls<<<N_GRAPHS, 64, 0, stream>>>(gsum, batch, W1, b1, W2, b2, out);
}